// Round 19
// baseline (694.668 us; speedup 1.0000x reference)
//
#include <hip/hip_runtime.h>
#include <math.h>

typedef unsigned short u16;
typedef u16 u16x8 __attribute__((ext_vector_type(8)));
typedef __bf16 bf16x8 __attribute__((ext_vector_type(8)));
typedef float f32x4 __attribute__((ext_vector_type(4)));

__device__ __forceinline__ u16 f2bf(float f) {
    union { float f; unsigned u; } v; v.f = f;
    unsigned r = v.u + 0x7fffu + ((v.u >> 16) & 1u);
    return (u16)(r >> 16);
}

__device__ __forceinline__ void gload16(const void* g, void* l) {
    __builtin_amdgcn_global_load_lds((const __attribute__((address_space(1))) void*)g,
                                     (__attribute__((address_space(3))) void*)l,
                                     16, 0, 0);
}

__device__ __forceinline__ float redsum16(float s) {
    s += __shfl_xor(s, 1, 64);
    s += __shfl_xor(s, 2, 64);
    s += __shfl_xor(s, 4, 64);
    s += __shfl_xor(s, 8, 64);
    return s;
}

// ---------------- fused NCHW->NHWC transpose + LN1 (block 1) ----------------
__global__ __launch_bounds__(256) void tl_k(const float* __restrict__ in,
                                            const float* __restrict__ g,
                                            const float* __restrict__ b,
                                            float* __restrict__ xbuf,
                                            u16* __restrict__ lnbuf) {
    __shared__ float T[192][33];
    __shared__ float MU[32], RS[32];
    const int t = threadIdx.x;
    const int bid = blockIdx.x;
    const int bb = bid >> 11;
    const int s0 = (bid & 2047) * 32;
    const float* src = in + (size_t)bb * 192 * 65536 + s0;
    const int sx = t & 31, cg = t >> 5;
#pragma unroll
    for (int i = 0; i < 24; i++) {
        int c = cg + i * 8;
        T[c][sx] = src[(size_t)c * 65536 + sx];
    }
    __syncthreads();
    {
        const int tok = t >> 3, sub = t & 7;
        float s = 0.f;
#pragma unroll
        for (int i = 0; i < 24; i++) s += T[sub + i * 8][tok];
        s += __shfl_xor(s, 1, 64); s += __shfl_xor(s, 2, 64); s += __shfl_xor(s, 4, 64);
        float mu = s * (1.f / 192.f);
        float q = 0.f;
#pragma unroll
        for (int i = 0; i < 24; i++) { float d = T[sub + i * 8][tok] - mu; q += d * d; }
        q += __shfl_xor(q, 1, 64); q += __shfl_xor(q, 2, 64); q += __shfl_xor(q, 4, 64);
        if (sub == 0) { MU[tok] = mu; RS[tok] = rsqrtf(q * (1.f / 192.f) + 1e-5f); }
    }
    __syncthreads();
    const size_t tokG0 = (size_t)bb * 65536 + s0;
#pragma unroll
    for (int i = 0; i < 3; i++) {
        int chunk = i * 256 + t;
        int tk = chunk / 24;
        int c0 = (chunk - tk * 24) * 8;
        float mu = MU[tk], rs = RS[tk];
        f32x4 g0 = *(const f32x4*)&g[c0], g1 = *(const f32x4*)&g[c0 + 4];
        f32x4 b0 = *(const f32x4*)&b[c0], b1 = *(const f32x4*)&b[c0 + 4];
        u16x8 ov;
#pragma unroll
        for (int e = 0; e < 4; e++) ov[e] = f2bf((T[c0 + e][tk] - mu) * rs * g0[e] + b0[e]);
#pragma unroll
        for (int e = 0; e < 4; e++) ov[e + 4] = f2bf((T[c0 + 4 + e][tk] - mu) * rs * g1[e] + b1[e]);
        *(u16x8*)&lnbuf[(tokG0 + tk) * 192 + c0] = ov;
    }
#pragma unroll
    for (int i = 0; i < 6; i++) {
        int chunk = i * 256 + t;
        int tk = chunk / 48;
        int c0 = (chunk - tk * 48) * 4;
        f32x4 v;
#pragma unroll
        for (int e = 0; e < 4; e++) v[e] = T[c0 + e][tk];
        *(f32x4*)&xbuf[(tokG0 + tk) * 192 + c0] = v;
    }
}

// ---------------- weight transpose + fp32->bf16: W[K,N] -> Wt[N,K] ----------------
__global__ __launch_bounds__(256) void wtrans(const float* __restrict__ w,
                                              u16* __restrict__ wt, int K, int N) {
    int idx = blockIdx.x * 256 + threadIdx.x;
    if (idx >= K * N) return;
    int n = idx / K, k = idx % K;
    wt[idx] = f2bf(w[(size_t)k * N + n]);
}

// ---------------- GEMM, K=192, BN=64, BM=256 (QKV): 512 threads, 8 waves ----------------
template <int ACT>
__global__ __launch_bounds__(512, 3) void gemm_small(const u16* __restrict__ A,
                                                     const u16* __restrict__ Wt,
                                                     const float* __restrict__ bias,
                                                     u16* __restrict__ outb,
                                                     int N, int Nb) {
    __shared__ __align__(16) u16 SMEM[18432];   // 36 KB: Bs (24 KB) then reused as Ct (36 KB)
    u16* Bs = SMEM;
    const int t = threadIdx.x, l = t & 63, w = t >> 6;
    const int nwg = gridDim.x, q8 = nwg >> 3;
    const int wg = (blockIdx.x & 7) * q8 + (blockIdx.x >> 3);
    const int bn = wg % Nb, bm = wg / Nb;
    const size_t m0 = (size_t)bm * 256;
    const int n0 = bn * 64;
    const int lc = l & 15, lg = l >> 4;

#pragma unroll
    for (int r = 0; r < 3; r++) {
        int f = r * 4096 + t * 8;
        int row = f / 192;
        int c = ((f - row * 192) >> 3) ^ (row & 7);
        gload16(Wt + (size_t)(n0 + row) * 192 + c * 8, &Bs[f]);
    }
    const u16* ga = A + (m0 + w * 32 + lc) * 192 + lg * 8;
    bf16x8 af[6][2];
#pragma unroll
    for (int ks = 0; ks < 6; ks++)
#pragma unroll
        for (int tm = 0; tm < 2; tm++)
            af[ks][tm] = *(const bf16x8*)(ga + tm * 3072 + ks * 32);

    f32x4 acc[2][4] = {};
    __syncthreads();
#pragma unroll
    for (int ks = 0; ks < 6; ks++) {
        bf16x8 bfr[4];
#pragma unroll
        for (int tn = 0; tn < 4; tn++) {
            int row = tn * 16 + lc;
            int p = (ks * 4 + lg) ^ (row & 7);
            bfr[tn] = *(const bf16x8*)&Bs[row * 192 + p * 8];
        }
#pragma unroll
        for (int tm = 0; tm < 2; tm++)
#pragma unroll
            for (int tn = 0; tn < 4; tn++)
                acc[tm][tn] = __builtin_amdgcn_mfma_f32_16x16x32_bf16(af[ks][tm], bfr[tn],
                                                                     acc[tm][tn], 0, 0, 0);
    }
    float bv[4];
#pragma unroll
    for (int tn = 0; tn < 4; tn++) bv[tn] = bias[n0 + tn * 16 + lc];
    __syncthreads();  // all Bs reads done
    u16* Ct = SMEM;   // [256][72] u16 = 36 KB
#pragma unroll
    for (int tm = 0; tm < 2; tm++)
#pragma unroll
        for (int tn = 0; tn < 4; tn++)
#pragma unroll
            for (int r = 0; r < 4; r++) {
                int row = w * 32 + tm * 16 + (lg << 2) + r;
                float v = acc[tm][tn][r] + bv[tn];
                Ct[row * 72 + tn * 16 + lc] = f2bf(v);
            }
    __syncthreads();
#pragma unroll
    for (int i = 0; i < 4; i++) {
        int row = i * 64 + (t >> 3), seg = t & 7;
        *(u16x8*)&outb[(m0 + row) * (size_t)N + n0 + seg * 8] =
            *(const u16x8*)&Ct[row * 72 + seg * 8];
    }
}

// ---------------- fused proj + residual + LN2 + MLP + residual ----------------
// DO_LN=1: epilogue2 writes res (fp32) + next-block LN1 (bf16).
// DO_LN=0: epilogue2 writes x'' DIRECTLY to NCHW output via LDS transpose bounce.
template <int DO_LN>
__global__ __launch_bounds__(512, 4) void proj_mlp(const u16* __restrict__ A,
                                                   const u16* __restrict__ PWt,
                                                   const float* __restrict__ pbias,
                                                   const float* __restrict__ g2,
                                                   const float* __restrict__ bl2,
                                                   const u16* __restrict__ W1t,
                                                   const float* __restrict__ b1,
                                                   const u16* __restrict__ W2t,
                                                   const float* __restrict__ b2,
                                                   float* __restrict__ res,
                                                   const float* __restrict__ gn,
                                                   const float* __restrict__ bn,
                                                   u16* __restrict__ lnout,
                                                   float* __restrict__ dout) {
    __shared__ __align__(16) u16 SMEM[40960];   // 80 KB overlay
    u16* Bs   = SMEM;            // phase1: 192*192 u16
    u16* ln2t = SMEM;            // phase2: 128*192 u16
    u16* W1s  = SMEM + 24576;    // 32*192 u16
    u16* W2s  = SMEM + 30720;    // 192*32 u16
    u16* Is   = SMEM + 36864;    // 128*32 u16
    const int t = threadIdx.x, l = t & 63, w = t >> 6;  // 8 waves
    const int nwg = gridDim.x, q8 = nwg >> 3;
    const int wg = (blockIdx.x & 7) * q8 + (blockIdx.x >> 3);
    const size_t m0 = (size_t)wg * 128;
    const int lc = l & 15, lg = l >> 4;

    f32x4 acc2[12] = {};   // phase1 accumulator -> x' carrier -> phase2 accumulator

    // ---- phase 1: proj GEMM (K=192, N=192) ----
#pragma unroll
    for (int r = 0; r < 9; r++) {
        int f = r * 4096 + t * 8;
        int row = f / 192;
        int c = ((f - row * 192) >> 3) ^ (row & 7);
        gload16(PWt + (size_t)row * 192 + c * 8, &Bs[f]);
    }
    {
        const u16* ga = A + (m0 + w * 16 + lc) * 192 + lg * 8;
        bf16x8 af[6];
#pragma unroll
        for (int ks = 0; ks < 6; ks++) af[ks] = *(const bf16x8*)(ga + ks * 32);

        __syncthreads();
#pragma unroll
        for (int ks = 0; ks < 6; ks++) {
#pragma unroll
            for (int grp = 0; grp < 3; grp++) {
                bf16x8 bfr[4];
#pragma unroll
                for (int tn = 0; tn < 4; tn++) {
                    int row = (grp * 4 + tn) * 16 + lc;
                    int p = (ks * 4 + lg) ^ (row & 7);
                    bfr[tn] = *(const bf16x8*)&Bs[row * 192 + p * 8];
                }
#pragma unroll
                for (int tn = 0; tn < 4; tn++)
                    acc2[grp * 4 + tn] = __builtin_amdgcn_mfma_f32_16x16x32_bf16(af[ks], bfr[tn],
                                                                                 acc2[grp * 4 + tn], 0, 0, 0);
            }
        }
        __syncthreads();  // all Bs reads done; SMEM reusable

        // ---- epilogue1: residual + in-register LN2; x' stays in acc2 ----
        float pbv[12], gv[12], bb[12];
#pragma unroll
        for (int tn = 0; tn < 12; tn++) {
            pbv[tn] = pbias[tn * 16 + lc];
            gv[tn] = g2[tn * 16 + lc];
            bb[tn] = bl2[tn * 16 + lc];
        }
#pragma unroll
        for (int r = 0; r < 4; r++) {
            int row = w * 16 + (lg << 2) + r;
            size_t base = (m0 + row) * 192;
            float v[12], s = 0.f;
#pragma unroll
            for (int tn = 0; tn < 12; tn++) {
                v[tn] = acc2[tn][r] + pbv[tn] + res[base + tn * 16 + lc];
                s += v[tn];
            }
            s = redsum16(s);
            float mu = s * (1.f / 192.f);
            float q = 0.f;
#pragma unroll
            for (int tn = 0; tn < 12; tn++) { float d = v[tn] - mu; q += d * d; }
            q = redsum16(q);
            float rstd = rsqrtf(q * (1.f / 192.f) + 1e-5f);
#pragma unroll
            for (int tn = 0; tn < 12; tn++) {
                acc2[tn][r] = v[tn];  // x' carried in the accumulator
                int col = tn * 16 + lc;
                float lnv = (v[tn] - mu) * rstd * gv[tn] + bb[tn];
                ln2t[row * 192 + (((col >> 3) ^ (row & 7)) << 3) + (col & 7)] = f2bf(lnv);
            }
        }
    }

#define STW1(c)                                                               \
    do {                                                                      \
        int f = t * 8;                                                        \
        int row = f / 192;                                                    \
        int cw = ((f - row * 192) >> 3) ^ (row & 7);                          \
        gload16(W1t + ((size_t)(c) * 32 + row) * 192 + cw * 8, &W1s[f]);      \
        if (t < 256) {                                                        \
            int f2 = (512 + t) * 8;                                           \
            int row2 = f2 / 192;                                              \
            int cw2 = ((f2 - row2 * 192) >> 3) ^ (row2 & 7);                  \
            gload16(W1t + ((size_t)(c) * 32 + row2) * 192 + cw2 * 8,          \
                    &W1s[f2]);                                                \
        }                                                                     \
    } while (0)
#define STW2(c)                                                               \
    do {                                                                      \
        int f = t * 8;                                                        \
        int row = f >> 5;                                                     \
        int cw = ((f >> 3) & 3) ^ ((row >> 1) & 3);                           \
        gload16(W2t + (size_t)row * 768 + (c) * 32 + cw * 8, &W2s[f]);        \
        if (t < 256) {                                                        \
            int f2 = (512 + t) * 8;                                           \
            int row2 = f2 >> 5;                                               \
            int cw2 = ((f2 >> 3) & 3) ^ ((row2 >> 1) & 3);                    \
            gload16(W2t + (size_t)row2 * 768 + (c) * 32 + cw2 * 8,            \
                    &W2s[f2]);                                                \
        }                                                                     \
    } while (0)

    STW1(0);
    STW2(0);
    __syncthreads();  // ln2t + W1s(0)/W2s(0) ready

    // ---- phase 2: MLP from ln2t; acc2 already holds x' ----
    bf16x8 af[6];
    {
        int row = w * 16 + lc;
#pragma unroll
        for (int ks = 0; ks < 6; ks++) {
            int p = (ks * 4 + lg) ^ (row & 7);
            af[ks] = *(const bf16x8*)&ln2t[row * 192 + p * 8];
        }
    }
#pragma unroll 1
    for (int c = 0; c < 24; c++) {
        // GEMM1: a1 = ln2 @ W1c
        f32x4 a1[2] = {};
#pragma unroll
        for (int ks = 0; ks < 6; ks++) {
            bf16x8 bfr[2];
#pragma unroll
            for (int tn = 0; tn < 2; tn++) {
                int row = tn * 16 + lc;
                int p = (ks * 4 + lg) ^ (row & 7);
                bfr[tn] = *(const bf16x8*)&W1s[row * 192 + p * 8];
            }
#pragma unroll
            for (int tn = 0; tn < 2; tn++)
                a1[tn] = __builtin_amdgcn_mfma_f32_16x16x32_bf16(af[ks], bfr[tn],
                                                                 a1[tn], 0, 0, 0);
        }
        // bias + GELU -> swizzled Is
        float b1v[2];
#pragma unroll
        for (int tn = 0; tn < 2; tn++) b1v[tn] = b1[c * 32 + tn * 16 + lc];
#pragma unroll
        for (int tn = 0; tn < 2; tn++)
#pragma unroll
            for (int r = 0; r < 4; r++) {
                int row = w * 16 + (lg << 2) + r;
                int col = tn * 16 + lc;
                float x = a1[tn][r] + b1v[tn];
                float u = x * x;
                float y = x * fmaf(-0.07136031f, u, -1.5957691f);
                float v = x * __builtin_amdgcn_rcpf(1.0f + __expf(y));
                int cw = (col >> 3) ^ ((row >> 1) & 3);
                Is[row * 32 + cw * 8 + (col & 7)] = f2bf(v);
            }
        __syncthreads();          // barrier A
        if (c < 23) STW1(c + 1);  // lands under GEMM2(c)
        // GEMM2: acc2 += inter @ W2c  (accumulating on top of x')
        bf16x8 a2;
        {
            int row = w * 16 + lc;
            int ch = lg ^ ((row >> 1) & 3);
            a2 = *(const bf16x8*)&Is[row * 32 + ch * 8];
        }
#pragma unroll
        for (int grp = 0; grp < 2; grp++) {
            bf16x8 b2f[6];
#pragma unroll
            for (int tn = 0; tn < 6; tn++) {
                int row = (grp * 6 + tn) * 16 + lc;
                int ch = lg ^ ((row >> 1) & 3);
                b2f[tn] = *(const bf16x8*)&W2s[row * 32 + ch * 8];
            }
#pragma unroll
            for (int tn = 0; tn < 6; tn++)
                acc2[grp * 6 + tn] = __builtin_amdgcn_mfma_f32_16x16x32_bf16(a2, b2f[tn],
                                                                            acc2[grp * 6 + tn], 0, 0, 0);
        }
        __syncthreads();          // barrier B
        if (c < 23) STW2(c + 1);  // lands under GEMM1(c+1)
    }
#undef STW1
#undef STW2
    // ---- epilogue2 ----
    float bv2[12];
#pragma unroll
    for (int tn = 0; tn < 12; tn++) bv2[tn] = b2[tn * 16 + lc];

    if (DO_LN) {
        float gv2[12], bb2[12];
#pragma unroll
        for (int tn = 0; tn < 12; tn++) { gv2[tn] = gn[tn * 16 + lc]; bb2[tn] = bn[tn * 16 + lc]; }
#pragma unroll
        for (int r = 0; r < 4; r++) {
            int row = w * 16 + (lg << 2) + r;
            size_t base = (m0 + row) * 192;
            float v[12], s = 0.f;
#pragma unroll
            for (int tn = 0; tn < 12; tn++) {
                v[tn] = acc2[tn][r] + bv2[tn];
                s += v[tn];
            }
#pragma unroll
            for (int tn = 0; tn < 12; tn++) res[base + tn * 16 + lc] = v[tn];
            s = redsum16(s);
            float mu = s * (1.f / 192.f);
            float q = 0.f;
#pragma unroll
            for (int tn = 0; tn < 12; tn++) { float d = v[tn] - mu; q += d * d; }
            q = redsum16(q);
            float rstd = rsqrtf(q * (1.f / 192.f) + 1e-5f);
#pragma unroll
            for (int tn = 0; tn < 12; tn++)
                lnout[base + tn * 16 + lc] = f2bf((v[tn] - mu) * rstd * gv2[tn] + bb2[tn]);
        }
    } else {
        // x'' straight to NCHW output: two [96][128] fp32 LDS bounces (stride 132)
        float* Ts = (float*)SMEM;
        const int bb = (int)(m0 >> 16);
        const size_t s_off = (size_t)(m0 & 65535);
#pragma unroll
        for (int p = 0; p < 2; p++) {
            if (p) __syncthreads();
#pragma unroll
            for (int j = 0; j < 6; j++) {
                const int tn = p * 6 + j;
                int colL = j * 16 + lc;
#pragma unroll
                for (int r = 0; r < 4; r++) {
                    int row = w * 16 + (lg << 2) + r;
                    Ts[colL * 132 + row] = acc2[tn][r] + bv2[tn];
                }
            }
            __syncthreads();
#pragma unroll
            for (int i = 0; i < 6; i++) {
                int cid = i * 512 + t;
                int rowL = cid >> 5;
                int c4 = cid & 31;
                f32x4 v4 = *(const f32x4*)&Ts[rowL * 132 + c4 * 4];
                *(f32x4*)&dout[((size_t)bb * 192 + p * 96 + rowL) * 65536 + s_off + c4 * 4] = v4;
            }
        }
    }
}

// ---------------- windowed attention: 1 wave per (window, head) ----------------
__global__ __launch_bounds__(64) void attn_k(const u16* __restrict__ qkv,
                                             const float* __restrict__ rpb,
                                             u16* __restrict__ aout, int shifted) {
    __shared__ __align__(16) u16 Vt[32][72];
    __shared__ __align__(16) u16 Ps[64][72];
    const int l = threadIdx.x;
    const int head = blockIdx.x;
    const int wy = blockIdx.y;
    const int b = wy >> 10, widx = wy & 1023;
    const int wh = widx >> 5, ww = widx & 31;
    const int soff = shifted ? 4 : 0;
    const int lc = l & 15;
    const int lg = l >> 4;

    {
        int i1 = l >> 3, j1 = l & 7;
        int hh = (wh * 8 + i1 + soff) & 255;
        int wc = (ww * 8 + j1 + soff) & 255;
        const u16* base = qkv + (((size_t)b * 256 + hh) * 256 + wc) * 576 + head * 32 + 384;
#pragma unroll
        for (int s = 0; s < 4; s++) {
            u16x8 v = *(const u16x8*)(base + s * 8);
#pragma unroll
            for (int e = 0; e < 8; e++) Vt[s * 8 + e][l] = v[e];
        }
    }

    bf16x8 qa[4], kb[4];
#pragma unroll
    for (int tm = 0; tm < 4; tm++) {
        int p = tm * 16 + lc;
        int pi = p >> 3, pj = p & 7;
        int hh = (wh * 8 + pi + soff) & 255;
        int wc = (ww * 8 + pj + soff) & 255;
        const u16* tp = qkv + (((size_t)b * 256 + hh) * 256 + wc) * 576 + head * 32;
        qa[tm] = *(const bf16x8*)(tp + lg * 8);
        kb[tm] = *(const bf16x8*)(tp + 192 + lg * 8);
    }

    f32x4 acc[4][4] = {};
    __builtin_amdgcn_s_setprio(1);
#pragma unroll
    for (int tm = 0; tm < 4; tm++)
#pragma unroll
        for (int tn = 0; tn < 4; tn++)
            acc[tm][tn] = __builtin_amdgcn_mfma_f32_16x16x32_bf16(qa[tm], kb[tn], acc[tm][tn], 0, 0, 0);
    __builtin_amdgcn_s_setprio(0);

    const float scale = 0.17677669529663687f;
    const float* rp = rpb + head * 225;
#pragma unroll
    for (int tm = 0; tm < 4; tm++) {
#pragma unroll
        for (int r = 0; r < 4; r++) {
            int p = tm * 16 + (lg << 2) + r;
            int pi = p >> 3, pj = p & 7;
            float sv[4];
#pragma unroll
            for (int tn = 0; tn < 4; tn++) {
                int qq = tn * 16 + lc;
                int qi = qq >> 3, qj = qq & 7;
                float xv = acc[tm][tn][r] * scale + rp[(pi - qi + 7) * 15 + (pj - qj + 7)];
                if (shifted) {
                    bool msk = (wh == 31 && ((pi < 4) != (qi < 4))) ||
                               (ww == 31 && ((pj < 4) != (qj < 4)));
                    if (msk) xv = -1e30f;
                }
                sv[tn] = xv;
            }
            float mx = fmaxf(fmaxf(sv[0], sv[1]), fmaxf(sv[2], sv[3]));
#pragma unroll
            for (int m = 1; m < 16; m <<= 1) mx = fmaxf(mx, __shfl_xor(mx, m, 64));
            float sum = 0.f;
#pragma unroll
            for (int tn = 0; tn < 4; tn++) { sv[tn] = __expf(sv[tn] - mx); sum += sv[tn]; }
#pragma unroll
            for (int m = 1; m < 16; m <<= 1) sum += __shfl_xor(sum, m, 64);
            float inv = 1.0f / sum;
#pragma unroll
            for (int tn = 0; tn < 4; tn++) Ps[p][tn * 16 + lc] = f2bf(sv[tn] * inv);
        }
    }
    __syncthreads();

    f32x4 o[4][2] = {};
    {
        bf16x8 pa[4], vb[2];
#pragma unroll
        for (int kk = 0; kk < 2; kk++) {
#pragma unroll
            for (int tm = 0; tm < 4; tm++) pa[tm] = *(const bf16x8*)&Ps[tm * 16 + lc][kk * 32 + lg * 8];
#pragma unroll
            for (int tn = 0; tn < 2; tn++) vb[tn] = *(const bf16x8*)&Vt[tn * 16 + lc][kk * 32 + lg * 8];
            __builtin_amdgcn_s_setprio(1);
#pragma unroll
            for (int tm = 0; tm < 4; tm++)
#pragma unroll
                for (int tn = 0; tn < 2; tn++)
                    o[tm][tn] = __builtin_amdgcn_mfma_f32_16x16x32_bf16(pa[tm], vb[tn], o[tm][tn], 0, 0, 0);
            __builtin_amdgcn_s_setprio(0);
        }
    }
#pragma unroll
    for (int tm = 0; tm < 4; tm++)
#pragma unroll
        for (int r = 0; r < 4; r++) {
            int p = tm * 16 + (lg << 2) + r;
            int pi = p >> 3, pj = p & 7;
            int h2 = (wh * 8 + pi + soff) & 255;
            int w2 = (ww * 8 + pj + soff) & 255;
            size_t t2 = ((size_t)b * 256 + h2) * 256 + w2;
#pragma unroll
            for (int tn = 0; tn < 2; tn++)
                aout[t2 * 192 + head * 32 + tn * 16 + lc] = f2bf(o[tm][tn][r]);
        }
}

extern "C" void kernel_launch(void* const* d_in, const int* in_sizes, int n_in,
                              void* d_out, int out_size, void* d_ws, size_t ws_size,
                              hipStream_t stream) {
    (void)in_sizes; (void)n_in; (void)out_size; (void)ws_size;
    const float* x_in = (const float*)d_in[0];

    char* ws = (char*)d_ws;
    float* xbuf = (float*)ws;                       // 100,663,296 B
    u16* lnbuf = (u16*)(ws + 100663296);            //  50,331,648 B
    u16* big   = (u16*)(ws + 150994944);            // 201,326,592 B
    u16* wts   = (u16*)(ws + 352321536);

    u16* qkvt[2]; u16* projt[2]; u16* w1t[2]; u16* w2t[2];
    for (int bi = 0; bi < 2; bi++) {
        size_t base = (size_t)bi * 442368;
        qkvt[bi]  = wts + base;
        projt[bi] = wts + base + 110592;
        w1t[bi]   = wts + base + 147456;
        w2t[bi]   = wts + base + 294912;
    }

    for (int bi = 0; bi < 2; bi++) {
        const int base = 1 + bi * 13;
        wtrans<<<dim3((110592 + 255) / 256), 256, 0, stream>>>((const float*)d_in[base + 2],  qkvt[bi],  192, 576);
        wtrans<<<dim3((36864  + 255) / 256), 256, 0, stream>>>((const float*)d_in[base + 5],  projt[bi], 192, 192);
        wtrans<<<dim3((147456 + 255) / 256), 256, 0, stream>>>((const float*)d_in[base + 9],  w1t[bi],   192, 768);
        wtrans<<<dim3((147456 + 255) / 256), 256, 0, stream>>>((const float*)d_in[base + 11], w2t[bi],   768, 192);
    }

    // fused NCHW->NHWC transpose + block-1 LN1
    tl_k<<<4096, 256, 0, stream>>>(x_in, (const float*)d_in[1], (const float*)d_in[2], xbuf, lnbuf);

    for (int bi = 0; bi < 2; bi++) {
        const int base = 1 + bi * 13;
        const float* qkv_b  = (const float*)d_in[base + 3];
        const float* rpb    = (const float*)d_in[base + 4];
        const float* proj_b = (const float*)d_in[base + 6];
        const float* ln2_g  = (const float*)d_in[base + 7];
        const float* ln2_b  = (const float*)d_in[base + 8];
        const float* b1     = (const float*)d_in[base + 10];
        const float* b2     = (const float*)d_in[base + 12];

        gemm_small<0><<<4608, 512, 0, stream>>>(lnbuf, qkvt[bi], qkv_b, big, 576, 9);
        attn_k<<<dim3(6, 2048), 64, 0, stream>>>(big, rpb, lnbuf, bi);
        if (bi == 0) {
            proj_mlp<1><<<1024, 512, 0, stream>>>(lnbuf, projt[bi], proj_b, ln2_g, ln2_b,
                                                  w1t[bi], b1, w2t[bi], b2, xbuf,
                                                  (const float*)d_in[14], (const float*)d_in[15], lnbuf,
                                                  nullptr);
        } else {
            proj_mlp<0><<<1024, 512, 0, stream>>>(lnbuf, projt[bi], proj_b, ln2_g, ln2_b,
                                                  w1t[bi], b1, w2t[bi], b2, xbuf,
                                                  nullptr, nullptr, nullptr,
                                                  (float*)d_out);
        }
    }
}

// Round 20
// 682.871 us; speedup vs baseline: 1.0173x; 1.0173x over previous
//
#include <hip/hip_runtime.h>
#include <math.h>

typedef unsigned short u16;
typedef u16 u16x8 __attribute__((ext_vector_type(8)));
typedef __bf16 bf16x8 __attribute__((ext_vector_type(8)));
typedef float f32x4 __attribute__((ext_vector_type(4)));

__device__ __forceinline__ u16 f2bf(float f) {
    union { float f; unsigned u; } v; v.f = f;
    unsigned r = v.u + 0x7fffu + ((v.u >> 16) & 1u);
    return (u16)(r >> 16);
}

__device__ __forceinline__ void gload16(const void* g, void* l) {
    __builtin_amdgcn_global_load_lds((const __attribute__((address_space(1))) void*)g,
                                     (__attribute__((address_space(3))) void*)l,
                                     16, 0, 0);
}

__device__ __forceinline__ float redsum16(float s) {
    s += __shfl_xor(s, 1, 64);
    s += __shfl_xor(s, 2, 64);
    s += __shfl_xor(s, 4, 64);
    s += __shfl_xor(s, 8, 64);
    return s;
}

// ---------------- fused NCHW->NHWC transpose + LN1 (block 1) ----------------
__global__ __launch_bounds__(256) void tl_k(const float* __restrict__ in,
                                            const float* __restrict__ g,
                                            const float* __restrict__ b,
                                            float* __restrict__ xbuf,
                                            u16* __restrict__ lnbuf) {
    __shared__ float T[192][33];
    __shared__ float MU[32], RS[32];
    const int t = threadIdx.x;
    const int bid = blockIdx.x;
    const int bb = bid >> 11;
    const int s0 = (bid & 2047) * 32;
    const float* src = in + (size_t)bb * 192 * 65536 + s0;
    const int sx = t & 31, cg = t >> 5;
#pragma unroll
    for (int i = 0; i < 24; i++) {
        int c = cg + i * 8;
        T[c][sx] = src[(size_t)c * 65536 + sx];
    }
    __syncthreads();
    {
        const int tok = t >> 3, sub = t & 7;
        float s = 0.f;
#pragma unroll
        for (int i = 0; i < 24; i++) s += T[sub + i * 8][tok];
        s += __shfl_xor(s, 1, 64); s += __shfl_xor(s, 2, 64); s += __shfl_xor(s, 4, 64);
        float mu = s * (1.f / 192.f);
        float q = 0.f;
#pragma unroll
        for (int i = 0; i < 24; i++) { float d = T[sub + i * 8][tok] - mu; q += d * d; }
        q += __shfl_xor(q, 1, 64); q += __shfl_xor(q, 2, 64); q += __shfl_xor(q, 4, 64);
        if (sub == 0) { MU[tok] = mu; RS[tok] = rsqrtf(q * (1.f / 192.f) + 1e-5f); }
    }
    __syncthreads();
    const size_t tokG0 = (size_t)bb * 65536 + s0;
#pragma unroll
    for (int i = 0; i < 3; i++) {
        int chunk = i * 256 + t;
        int tk = chunk / 24;
        int c0 = (chunk - tk * 24) * 8;
        float mu = MU[tk], rs = RS[tk];
        f32x4 g0 = *(const f32x4*)&g[c0], g1 = *(const f32x4*)&g[c0 + 4];
        f32x4 b0 = *(const f32x4*)&b[c0], b1 = *(const f32x4*)&b[c0 + 4];
        u16x8 ov;
#pragma unroll
        for (int e = 0; e < 4; e++) ov[e] = f2bf((T[c0 + e][tk] - mu) * rs * g0[e] + b0[e]);
#pragma unroll
        for (int e = 0; e < 4; e++) ov[e + 4] = f2bf((T[c0 + 4 + e][tk] - mu) * rs * g1[e] + b1[e]);
        *(u16x8*)&lnbuf[(tokG0 + tk) * 192 + c0] = ov;
    }
#pragma unroll
    for (int i = 0; i < 6; i++) {
        int chunk = i * 256 + t;
        int tk = chunk / 48;
        int c0 = (chunk - tk * 48) * 4;
        f32x4 v;
#pragma unroll
        for (int e = 0; e < 4; e++) v[e] = T[c0 + e][tk];
        *(f32x4*)&xbuf[(tokG0 + tk) * 192 + c0] = v;
    }
}

// ---------------- weight transpose + fp32->bf16: W[K,N] -> Wt[N,K] ----------------
__global__ __launch_bounds__(256) void wtrans(const float* __restrict__ w,
                                              u16* __restrict__ wt, int K, int N) {
    int idx = blockIdx.x * 256 + threadIdx.x;
    if (idx >= K * N) return;
    int n = idx / K, k = idx % K;
    wt[idx] = f2bf(w[(size_t)k * N + n]);
}

// ---------------- GEMM, K=192, BN=64 (QKV) ----------------
template <int ACT>
__global__ __launch_bounds__(256, 4) void gemm_small(const u16* __restrict__ A,
                                                     const u16* __restrict__ Wt,
                                                     const float* __restrict__ bias,
                                                     u16* __restrict__ outb,
                                                     int N, int Nb) {
    __shared__ __align__(16) u16 Bs[64 * 192];
    const int t = threadIdx.x, l = t & 63, w = t >> 6;
    const int nwg = gridDim.x, q8 = nwg >> 3;
    const int wg = (blockIdx.x & 7) * q8 + (blockIdx.x >> 3);
    const int bn = wg % Nb, bm = wg / Nb;
    const size_t m0 = (size_t)bm * 128;
    const int n0 = bn * 64;
    const int lc = l & 15, lg = l >> 4;

#pragma unroll
    for (int r = 0; r < 6; r++) {
        int f = r * 2048 + t * 8;
        int row = f / 192;
        int c = ((f - row * 192) >> 3) ^ (row & 7);
        gload16(Wt + (size_t)(n0 + row) * 192 + c * 8, &Bs[f]);
    }
    const u16* ga = A + (m0 + w * 32 + lc) * 192 + lg * 8;
    bf16x8 af[6][2];
#pragma unroll
    for (int ks = 0; ks < 6; ks++)
#pragma unroll
        for (int tm = 0; tm < 2; tm++)
            af[ks][tm] = *(const bf16x8*)(ga + tm * 3072 + ks * 32);

    f32x4 acc[2][4] = {};
    __syncthreads();
#pragma unroll
    for (int ks = 0; ks < 6; ks++) {
        bf16x8 bfr[4];
#pragma unroll
        for (int tn = 0; tn < 4; tn++) {
            int row = tn * 16 + lc;
            int p = (ks * 4 + lg) ^ (row & 7);
            bfr[tn] = *(const bf16x8*)&Bs[row * 192 + p * 8];
        }
#pragma unroll
        for (int tm = 0; tm < 2; tm++)
#pragma unroll
            for (int tn = 0; tn < 4; tn++)
                acc[tm][tn] = __builtin_amdgcn_mfma_f32_16x16x32_bf16(af[ks][tm], bfr[tn],
                                                                     acc[tm][tn], 0, 0, 0);
    }
    float bv[4];
#pragma unroll
    for (int tn = 0; tn < 4; tn++) bv[tn] = bias[n0 + tn * 16 + lc];
    __syncthreads();
    u16* Ct = Bs;
#pragma unroll
    for (int tm = 0; tm < 2; tm++)
#pragma unroll
        for (int tn = 0; tn < 4; tn++)
#pragma unroll
            for (int r = 0; r < 4; r++) {
                int row = w * 32 + tm * 16 + (lg << 2) + r;
                float v = acc[tm][tn][r] + bv[tn];
                Ct[row * 72 + tn * 16 + lc] = f2bf(v);
            }
    __syncthreads();
#pragma unroll
    for (int i = 0; i < 4; i++) {
        int row = i * 32 + (t >> 3), seg = t & 7;
        *(u16x8*)&outb[(m0 + row) * (size_t)N + n0 + seg * 8] =
            *(const u16x8*)&Ct[row * 72 + seg * 8];
    }
}

// ---------------- fused proj + residual + LN2 + MLP + residual ----------------
// DO_LN=1: epilogue2 writes res (fp32) + next-block LN1 (bf16).
// DO_LN=0: epilogue2 writes x'' DIRECTLY to NCHW output via LDS transpose bounce.
template <int DO_LN>
__global__ __launch_bounds__(512, 4) void proj_mlp(const u16* __restrict__ A,
                                                   const u16* __restrict__ PWt,
                                                   const float* __restrict__ pbias,
                                                   const float* __restrict__ g2,
                                                   const float* __restrict__ bl2,
                                                   const u16* __restrict__ W1t,
                                                   const float* __restrict__ b1,
                                                   const u16* __restrict__ W2t,
                                                   const float* __restrict__ b2,
                                                   float* __restrict__ res,
                                                   const float* __restrict__ gn,
                                                   const float* __restrict__ bn,
                                                   u16* __restrict__ lnout,
                                                   float* __restrict__ dout) {
    __shared__ __align__(16) u16 SMEM[40960];   // 80 KB overlay
    u16* Bs   = SMEM;            // phase1: 192*192 u16
    u16* ln2t = SMEM;            // phase2: 128*192 u16
    u16* W1s  = SMEM + 24576;    // 32*192 u16
    u16* W2s  = SMEM + 30720;    // 192*32 u16
    u16* Is   = SMEM + 36864;    // 128*32 u16
    const int t = threadIdx.x, l = t & 63, w = t >> 6;  // 8 waves
    const int nwg = gridDim.x, q8 = nwg >> 3;
    const int wg = (blockIdx.x & 7) * q8 + (blockIdx.x >> 3);
    const size_t m0 = (size_t)wg * 128;
    const int lc = l & 15, lg = l >> 4;

    f32x4 acc2[12] = {};   // phase1 accumulator -> x' carrier -> phase2 accumulator

    // ---- phase 1: proj GEMM (K=192, N=192) ----
#pragma unroll
    for (int r = 0; r < 9; r++) {
        int f = r * 4096 + t * 8;
        int row = f / 192;
        int c = ((f - row * 192) >> 3) ^ (row & 7);
        gload16(PWt + (size_t)row * 192 + c * 8, &Bs[f]);
    }
    {
        const u16* ga = A + (m0 + w * 16 + lc) * 192 + lg * 8;
        bf16x8 af[6];
#pragma unroll
        for (int ks = 0; ks < 6; ks++) af[ks] = *(const bf16x8*)(ga + ks * 32);

        __syncthreads();
#pragma unroll
        for (int ks = 0; ks < 6; ks++) {
#pragma unroll
            for (int grp = 0; grp < 3; grp++) {
                bf16x8 bfr[4];
#pragma unroll
                for (int tn = 0; tn < 4; tn++) {
                    int row = (grp * 4 + tn) * 16 + lc;
                    int p = (ks * 4 + lg) ^ (row & 7);
                    bfr[tn] = *(const bf16x8*)&Bs[row * 192 + p * 8];
                }
#pragma unroll
                for (int tn = 0; tn < 4; tn++)
                    acc2[grp * 4 + tn] = __builtin_amdgcn_mfma_f32_16x16x32_bf16(af[ks], bfr[tn],
                                                                                 acc2[grp * 4 + tn], 0, 0, 0);
            }
        }
        __syncthreads();  // all Bs reads done; SMEM reusable

        // ---- epilogue1: residual + in-register LN2; x' stays in acc2 ----
        float pbv[12], gv[12], bb[12];
#pragma unroll
        for (int tn = 0; tn < 12; tn++) {
            pbv[tn] = pbias[tn * 16 + lc];
            gv[tn] = g2[tn * 16 + lc];
            bb[tn] = bl2[tn * 16 + lc];
        }
#pragma unroll
        for (int r = 0; r < 4; r++) {
            int row = w * 16 + (lg << 2) + r;
            size_t base = (m0 + row) * 192;
            float v[12], s = 0.f;
#pragma unroll
            for (int tn = 0; tn < 12; tn++) {
                v[tn] = acc2[tn][r] + pbv[tn] + res[base + tn * 16 + lc];
                s += v[tn];
            }
            s = redsum16(s);
            float mu = s * (1.f / 192.f);
            float q = 0.f;
#pragma unroll
            for (int tn = 0; tn < 12; tn++) { float d = v[tn] - mu; q += d * d; }
            q = redsum16(q);
            float rstd = rsqrtf(q * (1.f / 192.f) + 1e-5f);
#pragma unroll
            for (int tn = 0; tn < 12; tn++) {
                acc2[tn][r] = v[tn];  // x' carried in the accumulator
                int col = tn * 16 + lc;
                float lnv = (v[tn] - mu) * rstd * gv[tn] + bb[tn];
                ln2t[row * 192 + (((col >> 3) ^ (row & 7)) << 3) + (col & 7)] = f2bf(lnv);
            }
        }
    }

#define STW1(c)                                                               \
    do {                                                                      \
        int f = t * 8;                                                        \
        int row = f / 192;                                                    \
        int cw = ((f - row * 192) >> 3) ^ (row & 7);                          \
        gload16(W1t + ((size_t)(c) * 32 + row) * 192 + cw * 8, &W1s[f]);      \
        if (t < 256) {                                                        \
            int f2 = (512 + t) * 8;                                           \
            int row2 = f2 / 192;                                              \
            int cw2 = ((f2 - row2 * 192) >> 3) ^ (row2 & 7);                  \
            gload16(W1t + ((size_t)(c) * 32 + row2) * 192 + cw2 * 8,          \
                    &W1s[f2]);                                                \
        }                                                                     \
    } while (0)
#define STW2(c)                                                               \
    do {                                                                      \
        int f = t * 8;                                                        \
        int row = f >> 5;                                                     \
        int cw = ((f >> 3) & 3) ^ ((row >> 1) & 3);                           \
        gload16(W2t + (size_t)row * 768 + (c) * 32 + cw * 8, &W2s[f]);        \
        if (t < 256) {                                                        \
            int f2 = (512 + t) * 8;                                           \
            int row2 = f2 >> 5;                                               \
            int cw2 = ((f2 >> 3) & 3) ^ ((row2 >> 1) & 3);                    \
            gload16(W2t + (size_t)row2 * 768 + (c) * 32 + cw2 * 8,            \
                    &W2s[f2]);                                                \
        }                                                                     \
    } while (0)

    STW1(0);
    STW2(0);
    __syncthreads();  // ln2t + W1s(0)/W2s(0) ready

    // ---- phase 2: MLP from ln2t; acc2 already holds x' ----
    bf16x8 af[6];
    {
        int row = w * 16 + lc;
#pragma unroll
        for (int ks = 0; ks < 6; ks++) {
            int p = (ks * 4 + lg) ^ (row & 7);
            af[ks] = *(const bf16x8*)&ln2t[row * 192 + p * 8];
        }
    }
#pragma unroll 1
    for (int c = 0; c < 24; c++) {
        // GEMM1: a1 = ln2 @ W1c
        f32x4 a1[2] = {};
#pragma unroll
        for (int ks = 0; ks < 6; ks++) {
            bf16x8 bfr[2];
#pragma unroll
            for (int tn = 0; tn < 2; tn++) {
                int row = tn * 16 + lc;
                int p = (ks * 4 + lg) ^ (row & 7);
                bfr[tn] = *(const bf16x8*)&W1s[row * 192 + p * 8];
            }
#pragma unroll
            for (int tn = 0; tn < 2; tn++)
                a1[tn] = __builtin_amdgcn_mfma_f32_16x16x32_bf16(af[ks], bfr[tn],
                                                                 a1[tn], 0, 0, 0);
        }
        // bias + GELU -> swizzled Is
        float b1v[2];
#pragma unroll
        for (int tn = 0; tn < 2; tn++) b1v[tn] = b1[c * 32 + tn * 16 + lc];
#pragma unroll
        for (int tn = 0; tn < 2; tn++)
#pragma unroll
            for (int r = 0; r < 4; r++) {
                int row = w * 16 + (lg << 2) + r;
                int col = tn * 16 + lc;
                float x = a1[tn][r] + b1v[tn];
                float u = x * x;
                float y = x * fmaf(-0.07136031f, u, -1.5957691f);
                float v = x * __builtin_amdgcn_rcpf(1.0f + __expf(y));
                int cw = (col >> 3) ^ ((row >> 1) & 3);
                Is[row * 32 + cw * 8 + (col & 7)] = f2bf(v);
            }
        __syncthreads();          // barrier A
        if (c < 23) STW1(c + 1);  // lands under GEMM2(c)
        // GEMM2: acc2 += inter @ W2c  (accumulating on top of x')
        bf16x8 a2;
        {
            int row = w * 16 + lc;
            int ch = lg ^ ((row >> 1) & 3);
            a2 = *(const bf16x8*)&Is[row * 32 + ch * 8];
        }
#pragma unroll
        for (int grp = 0; grp < 2; grp++) {
            bf16x8 b2f[6];
#pragma unroll
            for (int tn = 0; tn < 6; tn++) {
                int row = (grp * 6 + tn) * 16 + lc;
                int ch = lg ^ ((row >> 1) & 3);
                b2f[tn] = *(const bf16x8*)&W2s[row * 32 + ch * 8];
            }
#pragma unroll
            for (int tn = 0; tn < 6; tn++)
                acc2[grp * 6 + tn] = __builtin_amdgcn_mfma_f32_16x16x32_bf16(a2, b2f[tn],
                                                                            acc2[grp * 6 + tn], 0, 0, 0);
        }
        __syncthreads();          // barrier B
        if (c < 23) STW2(c + 1);  // lands under GEMM1(c+1)
    }
#undef STW1
#undef STW2
    // ---- epilogue2 ----
    float bv2[12];
#pragma unroll
    for (int tn = 0; tn < 12; tn++) bv2[tn] = b2[tn * 16 + lc];

    if (DO_LN) {
        float gv2[12], bb2[12];
#pragma unroll
        for (int tn = 0; tn < 12; tn++) { gv2[tn] = gn[tn * 16 + lc]; bb2[tn] = bn[tn * 16 + lc]; }
#pragma unroll
        for (int r = 0; r < 4; r++) {
            int row = w * 16 + (lg << 2) + r;
            size_t base = (m0 + row) * 192;
            float v[12], s = 0.f;
#pragma unroll
            for (int tn = 0; tn < 12; tn++) {
                v[tn] = acc2[tn][r] + bv2[tn];
                s += v[tn];
            }
#pragma unroll
            for (int tn = 0; tn < 12; tn++) res[base + tn * 16 + lc] = v[tn];
            s = redsum16(s);
            float mu = s * (1.f / 192.f);
            float q = 0.f;
#pragma unroll
            for (int tn = 0; tn < 12; tn++) { float d = v[tn] - mu; q += d * d; }
            q = redsum16(q);
            float rstd = rsqrtf(q * (1.f / 192.f) + 1e-5f);
#pragma unroll
            for (int tn = 0; tn < 12; tn++)
                lnout[base + tn * 16 + lc] = f2bf((v[tn] - mu) * rstd * gv2[tn] + bb2[tn]);
        }
    } else {
        // x'' straight to NCHW output: two [96][128] fp32 LDS bounces (stride 132)
        float* Ts = (float*)SMEM;
        const int bb = (int)(m0 >> 16);
        const size_t s_off = (size_t)(m0 & 65535);
#pragma unroll
        for (int p = 0; p < 2; p++) {
            if (p) __syncthreads();
#pragma unroll
            for (int j = 0; j < 6; j++) {
                const int tn = p * 6 + j;
                int colL = j * 16 + lc;
#pragma unroll
                for (int r = 0; r < 4; r++) {
                    int row = w * 16 + (lg << 2) + r;
                    Ts[colL * 132 + row] = acc2[tn][r] + bv2[tn];
                }
            }
            __syncthreads();
#pragma unroll
            for (int i = 0; i < 6; i++) {
                int cid = i * 512 + t;
                int rowL = cid >> 5;
                int c4 = cid & 31;
                f32x4 v4 = *(const f32x4*)&Ts[rowL * 132 + c4 * 4];
                *(f32x4*)&dout[((size_t)bb * 192 + p * 96 + rowL) * 65536 + s_off + c4 * 4] = v4;
            }
        }
    }
}

// ---------------- windowed attention: 1 wave per (window, head) ----------------
__global__ __launch_bounds__(64) void attn_k(const u16* __restrict__ qkv,
                                             const float* __restrict__ rpb,
                                             u16* __restrict__ aout, int shifted) {
    __shared__ __align__(16) u16 Vt[32][72];
    __shared__ __align__(16) u16 Ps[64][72];
    const int l = threadIdx.x;
    const int head = blockIdx.x;
    const int wy = blockIdx.y;
    const int b = wy >> 10, widx = wy & 1023;
    const int wh = widx >> 5, ww = widx & 31;
    const int soff = shifted ? 4 : 0;
    const int lc = l & 15;
    const int lg = l >> 4;

    {
        int i1 = l >> 3, j1 = l & 7;
        int hh = (wh * 8 + i1 + soff) & 255;
        int wc = (ww * 8 + j1 + soff) & 255;
        const u16* base = qkv + (((size_t)b * 256 + hh) * 256 + wc) * 576 + head * 32 + 384;
#pragma unroll
        for (int s = 0; s < 4; s++) {
            u16x8 v = *(const u16x8*)(base + s * 8);
#pragma unroll
            for (int e = 0; e < 8; e++) Vt[s * 8 + e][l] = v[e];
        }
    }

    bf16x8 qa[4], kb[4];
#pragma unroll
    for (int tm = 0; tm < 4; tm++) {
        int p = tm * 16 + lc;
        int pi = p >> 3, pj = p & 7;
        int hh = (wh * 8 + pi + soff) & 255;
        int wc = (ww * 8 + pj + soff) & 255;
        const u16* tp = qkv + (((size_t)b * 256 + hh) * 256 + wc) * 576 + head * 32;
        qa[tm] = *(const bf16x8*)(tp + lg * 8);
        kb[tm] = *(const bf16x8*)(tp + 192 + lg * 8);
    }

    f32x4 acc[4][4] = {};
    __builtin_amdgcn_s_setprio(1);
#pragma unroll
    for (int tm = 0; tm < 4; tm++)
#pragma unroll
        for (int tn = 0; tn < 4; tn++)
            acc[tm][tn] = __builtin_amdgcn_mfma_f32_16x16x32_bf16(qa[tm], kb[tn], acc[tm][tn], 0, 0, 0);
    __builtin_amdgcn_s_setprio(0);

    const float scale = 0.17677669529663687f;
    const float* rp = rpb + head * 225;
#pragma unroll
    for (int tm = 0; tm < 4; tm++) {
#pragma unroll
        for (int r = 0; r < 4; r++) {
            int p = tm * 16 + (lg << 2) + r;
            int pi = p >> 3, pj = p & 7;
            float sv[4];
#pragma unroll
            for (int tn = 0; tn < 4; tn++) {
                int qq = tn * 16 + lc;
                int qi = qq >> 3, qj = qq & 7;
                float xv = acc[tm][tn][r] * scale + rp[(pi - qi + 7) * 15 + (pj - qj + 7)];
                if (shifted) {
                    bool msk = (wh == 31 && ((pi < 4) != (qi < 4))) ||
                               (ww == 31 && ((pj < 4) != (qj < 4)));
                    if (msk) xv = -1e30f;
                }
                sv[tn] = xv;
            }
            float mx = fmaxf(fmaxf(sv[0], sv[1]), fmaxf(sv[2], sv[3]));
#pragma unroll
            for (int m = 1; m < 16; m <<= 1) mx = fmaxf(mx, __shfl_xor(mx, m, 64));
            float sum = 0.f;
#pragma unroll
            for (int tn = 0; tn < 4; tn++) { sv[tn] = __expf(sv[tn] - mx); sum += sv[tn]; }
#pragma unroll
            for (int m = 1; m < 16; m <<= 1) sum += __shfl_xor(sum, m, 64);
            float inv = 1.0f / sum;
#pragma unroll
            for (int tn = 0; tn < 4; tn++) Ps[p][tn * 16 + lc] = f2bf(sv[tn] * inv);
        }
    }
    __syncthreads();

    f32x4 o[4][2] = {};
    {
        bf16x8 pa[4], vb[2];
#pragma unroll
        for (int kk = 0; kk < 2; kk++) {
#pragma unroll
            for (int tm = 0; tm < 4; tm++) pa[tm] = *(const bf16x8*)&Ps[tm * 16 + lc][kk * 32 + lg * 8];
#pragma unroll
            for (int tn = 0; tn < 2; tn++) vb[tn] = *(const bf16x8*)&Vt[tn * 16 + lc][kk * 32 + lg * 8];
            __builtin_amdgcn_s_setprio(1);
#pragma unroll
            for (int tm = 0; tm < 4; tm++)
#pragma unroll
                for (int tn = 0; tn < 2; tn++)
                    o[tm][tn] = __builtin_amdgcn_mfma_f32_16x16x32_bf16(pa[tm], vb[tn], o[tm][tn], 0, 0, 0);
            __builtin_amdgcn_s_setprio(0);
        }
    }
#pragma unroll
    for (int tm = 0; tm < 4; tm++)
#pragma unroll
        for (int r = 0; r < 4; r++) {
            int p = tm * 16 + (lg << 2) + r;
            int pi = p >> 3, pj = p & 7;
            int h2 = (wh * 8 + pi + soff) & 255;
            int w2 = (ww * 8 + pj + soff) & 255;
            size_t t2 = ((size_t)b * 256 + h2) * 256 + w2;
#pragma unroll
            for (int tn = 0; tn < 2; tn++)
                aout[t2 * 192 + head * 32 + tn * 16 + lc] = f2bf(o[tm][tn][r]);
        }
}

extern "C" void kernel_launch(void* const* d_in, const int* in_sizes, int n_in,
                              void* d_out, int out_size, void* d_ws, size_t ws_size,
                              hipStream_t stream) {
    (void)in_sizes; (void)n_in; (void)out_size; (void)ws_size;
    const float* x_in = (const float*)d_in[0];

    char* ws = (char*)d_ws;
    float* xbuf = (float*)ws;                       // 100,663,296 B
    u16* lnbuf = (u16*)(ws + 100663296);            //  50,331,648 B
    u16* big   = (u16*)(ws + 150994944);            // 201,326,592 B
    u16* wts   = (u16*)(ws + 352321536);

    u16* qkvt[2]; u16* projt[2]; u16* w1t[2]; u16* w2t[2];
    for (int bi = 0; bi < 2; bi++) {
        size_t base = (size_t)bi * 442368;
        qkvt[bi]  = wts + base;
        projt[bi] = wts + base + 110592;
        w1t[bi]   = wts + base + 147456;
        w2t[bi]   = wts + base + 294912;
    }

    for (int bi = 0; bi < 2; bi++) {
        const int base = 1 + bi * 13;
        wtrans<<<dim3((110592 + 255) / 256), 256, 0, stream>>>((const float*)d_in[base + 2],  qkvt[bi],  192, 576);
        wtrans<<<dim3((36864  + 255) / 256), 256, 0, stream>>>((const float*)d_in[base + 5],  projt[bi], 192, 192);
        wtrans<<<dim3((147456 + 255) / 256), 256, 0, stream>>>((const float*)d_in[base + 9],  w1t[bi],   192, 768);
        wtrans<<<dim3((147456 + 255) / 256), 256, 0, stream>>>((const float*)d_in[base + 11], w2t[bi],   768, 192);
    }

    // fused NCHW->NHWC transpose + block-1 LN1
    tl_k<<<4096, 256, 0, stream>>>(x_in, (const float*)d_in[1], (const float*)d_in[2], xbuf, lnbuf);

    for (int bi = 0; bi < 2; bi++) {
        const int base = 1 + bi * 13;
        const float* qkv_b  = (const float*)d_in[base + 3];
        const float* rpb    = (const float*)d_in[base + 4];
        const float* proj_b = (const float*)d_in[base + 6];
        const float* ln2_g  = (const float*)d_in[base + 7];
        const float* ln2_b  = (const float*)d_in[base + 8];
        const float* b1     = (const float*)d_in[base + 10];
        const float* b2     = (const float*)d_in[base + 12];

        gemm_small<0><<<9216, 256, 0, stream>>>(lnbuf, qkvt[bi], qkv_b, big, 576, 9);
        attn_k<<<dim3(6, 2048), 64, 0, stream>>>(big, rpb, lnbuf, bi);
        if (bi == 0) {
            proj_mlp<1><<<1024, 512, 0, stream>>>(lnbuf, projt[bi], proj_b, ln2_g, ln2_b,
                                                  w1t[bi], b1, w2t[bi], b2, xbuf,
                                                  (const float*)d_in[14], (const float*)d_in[15], lnbuf,
                                                  nullptr);
        } else {
            proj_mlp<0><<<1024, 512, 0, stream>>>(lnbuf, projt[bi], proj_b, ln2_g, ln2_b,
                                                  w1t[bi], b1, w2t[bi], b2, xbuf,
                                                  nullptr, nullptr, nullptr,
                                                  (float*)d_out);
        }
    }
}